// Round 7
// baseline (8922.391 us; speedup 1.0000x reference)
//
#include <hip/hip_runtime.h>
#include <cmath>

#define WIDTH 384
#define HW 147456        // 384*384
#define CHW 4718592      // 32*384*384
#define NCH 32
#define NV 2048
#define NROWS 147456     // zf rows per scale

// ---------------------------------------------------------------------------
// numpy pairwise_sum replica, f32, contraction-proof.
// SQ=0: sum a[i]; SQ=1: sum (a[i]-mu)^2 (separate f32 sub, mul, add — like np).
// ---------------------------------------------------------------------------
template <int SQ>
__device__ float np_pw(const float* a, int n, float mu) {
  if (n < 8) {
    float res = 0.0f;
    for (int i = 0; i < n; i++) {
      float v = a[i];
      if (SQ) { float d = __fsub_rn(v, mu); v = __fmul_rn(d, d); }
      res = __fadd_rn(res, v);
    }
    return res;
  }
  if (n <= 128) {
    float r[8];
#pragma unroll
    for (int j = 0; j < 8; j++) {
      float v = a[j];
      if (SQ) { float d = __fsub_rn(v, mu); v = __fmul_rn(d, d); }
      r[j] = v;
    }
    int i;
    for (i = 8; i + 8 <= n; i += 8) {
#pragma unroll
      for (int j = 0; j < 8; j++) {
        float v = a[i + j];
        if (SQ) { float d = __fsub_rn(v, mu); v = __fmul_rn(d, d); }
        r[j] = __fadd_rn(r[j], v);
      }
    }
    float res = __fadd_rn(__fadd_rn(__fadd_rn(r[0], r[1]), __fadd_rn(r[2], r[3])),
                          __fadd_rn(__fadd_rn(r[4], r[5]), __fadd_rn(r[6], r[7])));
    for (; i < n; i++) {
      float v = a[i];
      if (SQ) { float d = __fsub_rn(v, mu); v = __fmul_rn(d, d); }
      res = __fadd_rn(res, v);
    }
    return res;
  }
  int n2 = n / 2; n2 -= n2 % 8;
  return __fadd_rn(np_pw<SQ>(a, n2, mu), np_pw<SQ>(a + n2, n - n2, mu));
}

// ---------------------------------------------------------------------------
// prep: ee[v] = numpy-pairwise |e|^2; WT = weights transposed to [layer][k][co]
// ---------------------------------------------------------------------------
__global__ __launch_bounds__(256) void prep_kernel(
    const float* __restrict__ pw1, const float* __restrict__ pw2,
    const float* __restrict__ rw1, const float* __restrict__ rw2,
    const float* __restrict__ emb, float* __restrict__ wt, float* __restrict__ ee) {
  int t = blockIdx.x * 256 + threadIdx.x;
  if (t < 147456) {
    int layer = t / 9216, r = t % 9216;
    int k = r / 32, co = r % 32;
    int set = layer >> 2, s = layer & 3;
    const float* src = set == 0 ? pw1 : set == 1 ? pw2 : set == 2 ? rw1 : rw2;
    wt[t] = src[s * 9216 + co * 288 + k];
  } else if (t < 147456 + NV) {
    int v = t - 147456;
    const float* e = emb + v * 32;
    float r[8];
#pragma unroll
    for (int j = 0; j < 8; j++) r[j] = __fmul_rn(e[j], e[j]);
#pragma unroll
    for (int i = 8; i < 32; i += 8)
#pragma unroll
      for (int j = 0; j < 8; j++) r[j] = __fadd_rn(r[j], __fmul_rn(e[i + j], e[i + j]));
    ee[v] = __fadd_rn(__fadd_rn(__fadd_rn(r[0], r[1]), __fadd_rn(r[2], r[3])),
                      __fadd_rn(__fadd_rn(r[4], r[5]), __fadd_rn(r[6], r[7])));
  }
}

// ---------------------------------------------------------------------------
// conv3x3, per-patch SAME zero pad. One thread = one pixel x 8 output
// channels (cb = block-uniform co-block; pp % 256 == 0 for all p).
// Per-co chain order = (ci, dy, dx) ascending fmaf — bit-identical to the
// 32-co version; invalid taps contribute fmaf(0,w,a)=a exactly.
// MODE 0: patch-major in -> patch-major out
// MODE 1: residual in (x - acc, image layout, fuses unfold) -> patch-major out
// MODE 2: patch-major in; fold: acc_img += zq*0.5 + (conv+b)*0.5
// ---------------------------------------------------------------------------
template <int MODE>
__global__ __launch_bounds__(256) void conv8_kernel(
    const float* __restrict__ in, const float* __restrict__ x,
    const float* __restrict__ accin, float* __restrict__ outb,
    const float* __restrict__ zqb, float* __restrict__ acc,
    const float* __restrict__ wt, const float* __restrict__ bias, int p, int nw) {
  int t = blockIdx.x * 256 + threadIdx.x;   // grid exact: 2304*256 = 589824
  int pp = p * p;
  int px = t % p; int t1 = t / p;
  int py = t1 % p; int t2 = t1 / p;
  int cb = t2 & 3;                          // block-uniform co block (8 co's)
  int n  = t2 >> 2;
  int i = n / nw, j = n % nw;

  int off[9]; bool msk[9];
#pragma unroll
  for (int dy = 0; dy < 3; dy++) {
    int ly = py + dy - 1;
    bool vy = (unsigned)ly < (unsigned)p;
    int cy = vy ? ly : 0;
#pragma unroll
    for (int dx = 0; dx < 3; dx++) {
      int lx = px + dx - 1;
      bool vx = (unsigned)lx < (unsigned)p;
      int cx = vx ? lx : 0;
      msk[dy * 3 + dx] = vy && vx;
      if (MODE == 1) off[dy * 3 + dx] = (i * p + cy) * WIDTH + (j * p + cx);
      else           off[dy * 3 + dx] = cy * p + cx;
    }
  }

  const float* pin = (MODE == 1) ? nullptr : in + (size_t)n * NCH * pp;

  float a[8];
#pragma unroll
  for (int u = 0; u < 8; u++) a[u] = 0.0f;

  for (int ci = 0; ci < NCH; ci++) {
    float tv[9];
#pragma unroll
    for (int k = 0; k < 9; k++) {
      float v;
      if (MODE == 1) {
        size_t ad = (size_t)ci * HW + off[k];
        v = __fsub_rn(x[ad], accin[ad]);
      } else {
        v = pin[(size_t)ci * pp + off[k]];
      }
      tv[k] = msk[k] ? v : 0.0f;
    }
    const float* wp = wt + ci * 288 + cb * 8;   // uniform -> s_load
#pragma unroll
    for (int k = 0; k < 9; k++) {
#pragma unroll
      for (int u = 0; u < 8; u++)
        a[u] = fmaf(tv[k], wp[k * 32 + u], a[u]);
    }
  }

#pragma unroll
  for (int u = 0; u < 8; u++) {
    int co = cb * 8 + u;
    float r = __fadd_rn(a[u], bias[co]);
    if (MODE == 2) {
      size_t img = (size_t)co * HW + (size_t)(i * p + py) * WIDTH + (j * p + px);
      size_t pt  = (size_t)n * NCH * pp + (size_t)co * pp + (size_t)py * p + px;
      float dec = __fadd_rn(__fmul_rn(zqb[pt], 0.5f), __fmul_rn(r, 0.5f));
      acc[img] = __fadd_rn(acc[img], dec);
    } else {
      outb[(size_t)n * NCH * pp + (size_t)co * pp + (size_t)py * p + px] = r;
    }
  }
}

// ---------------------------------------------------------------------------
// GroupNorm stats, numpy-exact (unchanged).
// ---------------------------------------------------------------------------
__global__ __launch_bounds__(64) void gn_stats_kernel(
    const float* __restrict__ buf, float2* __restrict__ stats, int p) {
  __shared__ float lds[8][8];
  __shared__ float mus[8];
  int gi = threadIdx.x >> 3, l = threadIdx.x & 7;
  int grp = blockIdx.x * 8 + gi;
  int pp = p * p, ne = 4 * pp, chunk = ne >> 3;
  const float* base = buf + ((size_t)(grp >> 3) * NCH + (size_t)(grp & 7) * 4) * pp;

  lds[gi][l] = np_pw<0>(base + l * chunk, chunk, 0.0f);
  __syncthreads();
  if (l == 0) {
    float* r = lds[gi];
    float s = __fadd_rn(__fadd_rn(__fadd_rn(r[0], r[1]), __fadd_rn(r[2], r[3])),
                        __fadd_rn(__fadd_rn(r[4], r[5]), __fadd_rn(r[6], r[7])));
    mus[gi] = __fdiv_rn(s, (float)ne);
  }
  __syncthreads();
  float mu = mus[gi];
  lds[gi][l] = np_pw<1>(base + l * chunk, chunk, mu);
  __syncthreads();
  if (l == 0) {
    float* r = lds[gi];
    float s2 = __fadd_rn(__fadd_rn(__fadd_rn(r[0], r[1]), __fadd_rn(r[2], r[3])),
                         __fadd_rn(__fadd_rn(r[4], r[5]), __fadd_rn(r[6], r[7])));
    float var = __fdiv_rn(s2, (float)ne);
    float rs = __fdiv_rn(1.0f, __fsqrt_rn(__fadd_rn(var, 1e-5f)));
    stats[grp] = make_float2(mu, rs);
  }
}

// ---------------------------------------------------------------------------
// GN affine + exact GELU (unchanged; erf = f64 erf rounded to f32).
// ---------------------------------------------------------------------------
__global__ __launch_bounds__(256) void gn_gelu_kernel(
    float* __restrict__ buf, const float2* __restrict__ stats,
    const float* __restrict__ gamma, const float* __restrict__ beta, int p) {
  int t = blockIdx.x * 256 + threadIdx.x;
  int pp = p * p;
  int t2 = t / pp;
  int c = t2 % NCH;
  int n = t2 / NCH;
  float2 st = stats[n * 8 + (c >> 2)];
  float v = __fadd_rn(__fmul_rn(__fmul_rn(__fsub_rn(buf[t], st.x), st.y), gamma[c]), beta[c]);
  float tt = __fdiv_rn(v, 1.41421356237309504880f);
  float e = (float)erf((double)tt);
  buf[t] = __fmul_rn(__fmul_rn(0.5f, v), __fadd_rn(1.0f, e));
}

// ---------------------------------------------------------------------------
// Argmin pass 1: per (row, vocab-segment of 512) partial argmin.
// Scores identical f32 chains as before; strict < = first occurrence within
// the segment. seg is block-uniform (NROWS % 256 == 0).
// ---------------------------------------------------------------------------
__global__ __launch_bounds__(256) void argmin_part_kernel(
    const float* __restrict__ z, const float* __restrict__ emb,
    const float* __restrict__ ee, float* __restrict__ cd, int* __restrict__ ci) {
  int t = blockIdx.x * 256 + threadIdx.x;   // grid exact: 2304*256 = 589824
  int seg = t / NROWS;                       // block-uniform
  int r = t - seg * NROWS;
  const float* zr = z + (size_t)r * 32;

  float zv[32];
#pragma unroll
  for (int q = 0; q < 32; q++) zv[q] = zr[q];

  // zz: numpy pairwise over 32 squares (identical in every segment)
  float rr[8];
#pragma unroll
  for (int j = 0; j < 8; j++) rr[j] = __fmul_rn(zv[j], zv[j]);
#pragma unroll
  for (int i = 8; i < 32; i += 8)
#pragma unroll
    for (int j = 0; j < 8; j++) rr[j] = __fadd_rn(rr[j], __fmul_rn(zv[i + j], zv[i + j]));
  float zz = __fadd_rn(__fadd_rn(__fadd_rn(rr[0], rr[1]), __fadd_rn(rr[2], rr[3])),
                       __fadd_rn(__fadd_rn(rr[4], rr[5]), __fadd_rn(rr[6], rr[7])));

  int v0 = seg * (NV / 4);
  float best = 3.402823466e+38f;
  int bi = v0;
  for (int v = v0; v < v0 + NV / 4; v += 4) {
    const float* e0 = emb + (size_t)v * 32;  // uniform -> scalar loads
    float m0 = 0.0f, m1 = 0.0f, m2 = 0.0f, m3 = 0.0f;
#pragma unroll
    for (int q = 0; q < 32; q++) {
      m0 = fmaf(zv[q], e0[q], m0);
      m1 = fmaf(zv[q], e0[32 + q], m1);
      m2 = fmaf(zv[q], e0[64 + q], m2);
      m3 = fmaf(zv[q], e0[96 + q], m3);
    }
    float d0 = __fsub_rn(__fadd_rn(zz, ee[v]),     __fmul_rn(2.0f, m0));
    float d1 = __fsub_rn(__fadd_rn(zz, ee[v + 1]), __fmul_rn(2.0f, m1));
    float d2 = __fsub_rn(__fadd_rn(zz, ee[v + 2]), __fmul_rn(2.0f, m2));
    float d3 = __fsub_rn(__fadd_rn(zz, ee[v + 3]), __fmul_rn(2.0f, m3));
    if (d0 < best) { best = d0; bi = v; }
    if (d1 < best) { best = d1; bi = v + 1; }
    if (d2 < best) { best = d2; bi = v + 2; }
    if (d3 < best) { best = d3; bi = v + 3; }
  }
  cd[t] = best;
  ci[t] = bi;
}

// ---------------------------------------------------------------------------
// Argmin pass 2: merge 4 segment candidates (ascending seg + strict < =
// global first occurrence), gather zq, write idx, SSE partials.
// ---------------------------------------------------------------------------
__global__ __launch_bounds__(256) void argmin_fin_kernel(
    const float* __restrict__ z, const float* __restrict__ emb,
    const float* __restrict__ cd, const int* __restrict__ ci,
    float* __restrict__ zq, float* __restrict__ idxout, double* __restrict__ part) {
  __shared__ double red[256];
  int r = blockIdx.x * 256 + threadIdx.x;   // grid exact: 576*256 rows
  float best = cd[r];
  int bi = ci[r];
#pragma unroll
  for (int sg = 1; sg < 4; sg++) {
    float d = cd[(size_t)sg * NROWS + r];
    int x = ci[(size_t)sg * NROWS + r];
    if (d < best) { best = d; bi = x; }
  }

  const float* zr = z + (size_t)r * 32;
  double sse = 0.0;
#pragma unroll
  for (int q = 0; q < 32; q++) {
    float e = emb[bi * 32 + q];
    zq[(size_t)r * 32 + q] = e;
    double dd = (double)e - (double)zr[q];
    sse += dd * dd;
  }
  idxout[r] = (float)bi;

  red[threadIdx.x] = sse;
  __syncthreads();
  for (int st = 128; st > 0; st >>= 1) {
    if (threadIdx.x < st) red[threadIdx.x] += red[threadIdx.x + st];
    __syncthreads();
  }
  if (threadIdx.x == 0) part[blockIdx.x] = red[0];
}

__global__ __launch_bounds__(256) void sigmoid_kernel(
    const float* __restrict__ acc, float* __restrict__ out) {
  int t = blockIdx.x * 256 + threadIdx.x;
  out[t] = (float)(1.0 / (1.0 + exp(-(double)acc[t])));
}

__global__ void loss_kernel(const double* __restrict__ part, float* __restrict__ out) {
  double tot = 0.0;
  for (int s = 0; s < 4; s++) {
    double sse = 0.0;
    for (int b = 0; b < 576; b++) sse += part[s * 1024 + b];
    tot += 1.25 * sse / 4718592.0;
  }
  out[0] = (float)tot;
}

// ---------------------------------------------------------------------------
extern "C" void kernel_launch(void* const* d_in, const int* in_sizes, int n_in,
                              void* d_out, int out_size, void* d_ws, size_t ws_size,
                              hipStream_t stream) {
  const float* X   = (const float*)d_in[0];
  const float* EMB = (const float*)d_in[1];
  const float* PW1 = (const float*)d_in[2];
  const float* PB1 = (const float*)d_in[3];
  const float* PG  = (const float*)d_in[4];
  const float* PBT = (const float*)d_in[5];
  const float* PW2 = (const float*)d_in[6];
  const float* PB2 = (const float*)d_in[7];
  const float* RW1 = (const float*)d_in[8];
  const float* RB1 = (const float*)d_in[9];
  const float* RG  = (const float*)d_in[10];
  const float* RBT = (const float*)d_in[11];
  const float* RW2 = (const float*)d_in[12];
  const float* RB2 = (const float*)d_in[13];
  float* out = (float*)d_out;

  // workspace layout (~59 MiB):
  //   EE    @ 0         (8,192)       f32 |e|^2
  //   WT    @ 8192      (589,824)     f32 transposed weights [16][288][32]
  //   STATS @ 598016    (36,864)      float2 per-(n,g) mu/rs
  //   PART  @ 634880    (32,768)      f64 SSE partials
  //   CD    @ 667648    (2,359,296)   f32 per-(seg,row) best score
  //   CI    @ 3026944   (2,359,296)   i32 per-(seg,row) best idx
  //   P     @ 5386240   (18,874,368)  f32 patch-major buffer
  //   H     @ 24260608  (18,874,368)  f32 patch-major buffer
  //   ACC   @ 43134976  (18,874,368)  f32 image-layout accumulator
  char* w = (char*)d_ws;
  float*  EE    = (float*)(w);
  float*  WT    = (float*)(w + 8192UL);
  float2* STATS = (float2*)(w + 598016UL);
  double* PART  = (double*)(w + 634880UL);
  float*  CD    = (float*)(w + 667648UL);
  int*    CI    = (int*)(w + 3026944UL);
  float*  P     = (float*)(w + 5386240UL);
  float*  H     = (float*)(w + 24260608UL);
  float*  ACC   = (float*)(w + 43134976UL);

  hipMemsetAsync(ACC, 0, 18874368UL, stream);
  prep_kernel<<<584, 256, 0, stream>>>(PW1, PW2, RW1, RW2, EMB, WT, EE);

  const int PS[4] = {16, 32, 48, 64};
  for (int s = 0; s < 4; s++) {
    int p = PS[s], nw = 384 / p, N = nw * nw;
    const float* wt_p1 = WT + (0 * 4 + s) * 9216;
    const float* wt_p2 = WT + (1 * 4 + s) * 9216;
    const float* wt_r1 = WT + (2 * 4 + s) * 9216;
    const float* wt_r2 = WT + (3 * 4 + s) * 9216;

    // conv_block #1 (fused unfold): (x - acc) -> H, GN+GELU in H, H -> P (z)
    conv8_kernel<1><<<2304, 256, 0, stream>>>(nullptr, X, ACC, H, nullptr, nullptr,
                                              wt_p1, PB1 + s * 32, p, nw);
    gn_stats_kernel<<<N, 64, 0, stream>>>(H, STATS, p);
    gn_gelu_kernel<<<18432, 256, 0, stream>>>(H, STATS, PG + s * 32, PBT + s * 32, p);
    conv8_kernel<0><<<2304, 256, 0, stream>>>(H, nullptr, nullptr, P, nullptr, nullptr,
                                              wt_p2, PB2 + s * 32, p, nw);
    // quantize: z (P) -> partial argmins -> idx, zq into H, SSE partials
    argmin_part_kernel<<<2304, 256, 0, stream>>>(P, EMB, EE, CD, CI);
    argmin_fin_kernel<<<576, 256, 0, stream>>>(P, EMB, CD, CI, H,
                                               out + 4718592 + s * 147456, PART + s * 1024);
    // residual conv_block on zq: H -> P, GN+GELU in P, conv+fold into ACC
    conv8_kernel<0><<<2304, 256, 0, stream>>>(H, nullptr, nullptr, P, nullptr, nullptr,
                                              wt_r1, RB1 + s * 32, p, nw);
    gn_stats_kernel<<<N, 64, 0, stream>>>(P, STATS, p);
    gn_gelu_kernel<<<18432, 256, 0, stream>>>(P, STATS, RG + s * 32, RBT + s * 32, p);
    conv8_kernel<2><<<2304, 256, 0, stream>>>(P, nullptr, nullptr, nullptr, H, ACC,
                                              wt_r2, RB2 + s * 32, p, nw);
  }

  sigmoid_kernel<<<18432, 256, 0, stream>>>(ACC, out);
  loss_kernel<<<1, 1, 0, stream>>>(PART, out + 5308416);
}

// Round 8
// 3477.794 us; speedup vs baseline: 2.5655x; 2.5655x over previous
//
#include <hip/hip_runtime.h>
#include <cmath>

#define WIDTH 384
#define HW 147456        // 384*384
#define CHW 4718592      // 32*384*384
#define NCH 32
#define NV 2048
#define NROWS 147456     // zf rows per scale

// ---------------------------------------------------------------------------
// numpy pairwise_sum replica, f32, contraction-proof.
// ---------------------------------------------------------------------------
template <int SQ>
__device__ float np_pw(const float* a, int n, float mu) {
  if (n < 8) {
    float res = 0.0f;
    for (int i = 0; i < n; i++) {
      float v = a[i];
      if (SQ) { float d = __fsub_rn(v, mu); v = __fmul_rn(d, d); }
      res = __fadd_rn(res, v);
    }
    return res;
  }
  if (n <= 128) {
    float r[8];
#pragma unroll
    for (int j = 0; j < 8; j++) {
      float v = a[j];
      if (SQ) { float d = __fsub_rn(v, mu); v = __fmul_rn(d, d); }
      r[j] = v;
    }
    int i;
    for (i = 8; i + 8 <= n; i += 8) {
#pragma unroll
      for (int j = 0; j < 8; j++) {
        float v = a[i + j];
        if (SQ) { float d = __fsub_rn(v, mu); v = __fmul_rn(d, d); }
        r[j] = __fadd_rn(r[j], v);
      }
    }
    float res = __fadd_rn(__fadd_rn(__fadd_rn(r[0], r[1]), __fadd_rn(r[2], r[3])),
                          __fadd_rn(__fadd_rn(r[4], r[5]), __fadd_rn(r[6], r[7])));
    for (; i < n; i++) {
      float v = a[i];
      if (SQ) { float d = __fsub_rn(v, mu); v = __fmul_rn(d, d); }
      res = __fadd_rn(res, v);
    }
    return res;
  }
  int n2 = n / 2; n2 -= n2 % 8;
  return __fadd_rn(np_pw<SQ>(a, n2, mu), np_pw<SQ>(a + n2, n - n2, mu));
}

// ---------------------------------------------------------------------------
// prep: ee[v] = numpy-pairwise |e|^2; WT = weights transposed to [layer][k][co]
// ---------------------------------------------------------------------------
__global__ __launch_bounds__(256) void prep_kernel(
    const float* __restrict__ pw1, const float* __restrict__ pw2,
    const float* __restrict__ rw1, const float* __restrict__ rw2,
    const float* __restrict__ emb, float* __restrict__ wt, float* __restrict__ ee) {
  int t = blockIdx.x * 256 + threadIdx.x;
  if (t < 147456) {
    int layer = t / 9216, r = t % 9216;
    int k = r / 32, co = r % 32;
    int set = layer >> 2, s = layer & 3;
    const float* src = set == 0 ? pw1 : set == 1 ? pw2 : set == 2 ? rw1 : rw2;
    wt[t] = src[s * 9216 + co * 288 + k];
  } else if (t < 147456 + NV) {
    int v = t - 147456;
    const float* e = emb + v * 32;
    float r[8];
#pragma unroll
    for (int j = 0; j < 8; j++) r[j] = __fmul_rn(e[j], e[j]);
#pragma unroll
    for (int i = 8; i < 32; i += 8)
#pragma unroll
      for (int j = 0; j < 8; j++) r[j] = __fadd_rn(r[j], __fmul_rn(e[i + j], e[i + j]));
    ee[v] = __fadd_rn(__fadd_rn(__fadd_rn(r[0], r[1]), __fadd_rn(r[2], r[3])),
                      __fadd_rn(__fadd_rn(r[4], r[5]), __fadd_rn(r[6], r[7])));
  }
}

// ---------------------------------------------------------------------------
// conv3x3 (round-6 known-good): one thread = one pixel, ALL 32 co.
// Per-co chain order = (ci, dy, dx) ascending fmaf; invalid taps = exact
// identities. Weights via wave-uniform scalar loads from WT [k][co].
// MODE 0: patch-major in -> patch-major out
// MODE 1: residual in (x - acc, image layout, fuses unfold) -> patch-major out
// MODE 2: patch-major in; fold: acc_img += zq*0.5 + (conv+b)*0.5
// ---------------------------------------------------------------------------
template <int MODE>
__global__ __launch_bounds__(256) void conv32_kernel(
    const float* __restrict__ in, const float* __restrict__ x,
    const float* __restrict__ accin, float* __restrict__ outb,
    const float* __restrict__ zqb, float* __restrict__ acc,
    const float* __restrict__ wt, const float* __restrict__ bias, int p, int nw) {
  int t = blockIdx.x * 256 + threadIdx.x;   // grid exact: 576*256 = 147456
  int pp = p * p;
  int px = t % p; int t1 = t / p;
  int py = t1 % p;
  int n  = t1 / p;
  int i = n / nw, j = n % nw;

  int off[9]; bool msk[9];
#pragma unroll
  for (int dy = 0; dy < 3; dy++) {
    int ly = py + dy - 1;
    bool vy = (unsigned)ly < (unsigned)p;
    int cy = vy ? ly : 0;
#pragma unroll
    for (int dx = 0; dx < 3; dx++) {
      int lx = px + dx - 1;
      bool vx = (unsigned)lx < (unsigned)p;
      int cx = vx ? lx : 0;
      msk[dy * 3 + dx] = vy && vx;
      if (MODE == 1) off[dy * 3 + dx] = (i * p + cy) * WIDTH + (j * p + cx);
      else           off[dy * 3 + dx] = cy * p + cx;
    }
  }

  const float* pin = (MODE == 1) ? nullptr : in + (size_t)n * NCH * pp;

  float a[NCH];
#pragma unroll
  for (int co = 0; co < NCH; co++) a[co] = 0.0f;

  for (int ci = 0; ci < NCH; ci++) {
    float tv[9];
#pragma unroll
    for (int k = 0; k < 9; k++) {
      float v;
      if (MODE == 1) {
        size_t ad = (size_t)ci * HW + off[k];
        v = __fsub_rn(x[ad], accin[ad]);
      } else {
        v = pin[(size_t)ci * pp + off[k]];
      }
      tv[k] = msk[k] ? v : 0.0f;
    }
    const float* wp = wt + ci * 288;        // [k][co], uniform -> s_load
#pragma unroll
    for (int k = 0; k < 9; k++) {
#pragma unroll
      for (int co = 0; co < NCH; co++)
        a[co] = fmaf(tv[k], wp[k * 32 + co], a[co]);
    }
  }

#pragma unroll
  for (int co = 0; co < NCH; co++) {
    float r = __fadd_rn(a[co], bias[co]);
    if (MODE == 2) {
      size_t img = (size_t)co * HW + (size_t)(i * p + py) * WIDTH + (j * p + px);
      size_t pt  = (size_t)n * NCH * pp + (size_t)co * pp + (size_t)py * p + px;
      float dec = __fadd_rn(__fmul_rn(zqb[pt], 0.5f), __fmul_rn(r, 0.5f));
      acc[img] = __fadd_rn(acc[img], dec);
    } else {
      outb[(size_t)n * NCH * pp + (size_t)co * pp + (size_t)py * p + px] = r;
    }
  }
}

// ---------------------------------------------------------------------------
// GroupNorm stats, numpy-exact (unchanged).
// ---------------------------------------------------------------------------
__global__ __launch_bounds__(64) void gn_stats_kernel(
    const float* __restrict__ buf, float2* __restrict__ stats, int p) {
  __shared__ float lds[8][8];
  __shared__ float mus[8];
  int gi = threadIdx.x >> 3, l = threadIdx.x & 7;
  int grp = blockIdx.x * 8 + gi;
  int pp = p * p, ne = 4 * pp, chunk = ne >> 3;
  const float* base = buf + ((size_t)(grp >> 3) * NCH + (size_t)(grp & 7) * 4) * pp;

  lds[gi][l] = np_pw<0>(base + l * chunk, chunk, 0.0f);
  __syncthreads();
  if (l == 0) {
    float* r = lds[gi];
    float s = __fadd_rn(__fadd_rn(__fadd_rn(r[0], r[1]), __fadd_rn(r[2], r[3])),
                        __fadd_rn(__fadd_rn(r[4], r[5]), __fadd_rn(r[6], r[7])));
    mus[gi] = __fdiv_rn(s, (float)ne);
  }
  __syncthreads();
  float mu = mus[gi];
  lds[gi][l] = np_pw<1>(base + l * chunk, chunk, mu);
  __syncthreads();
  if (l == 0) {
    float* r = lds[gi];
    float s2 = __fadd_rn(__fadd_rn(__fadd_rn(r[0], r[1]), __fadd_rn(r[2], r[3])),
                         __fadd_rn(__fadd_rn(r[4], r[5]), __fadd_rn(r[6], r[7])));
    float var = __fdiv_rn(s2, (float)ne);
    float rs = __fdiv_rn(1.0f, __fsqrt_rn(__fadd_rn(var, 1e-5f)));
    stats[grp] = make_float2(mu, rs);
  }
}

// ---------------------------------------------------------------------------
// GN affine + exact GELU (unchanged; erf = f64 erf rounded to f32).
// ---------------------------------------------------------------------------
__global__ __launch_bounds__(256) void gn_gelu_kernel(
    float* __restrict__ buf, const float2* __restrict__ stats,
    const float* __restrict__ gamma, const float* __restrict__ beta, int p) {
  int t = blockIdx.x * 256 + threadIdx.x;
  int pp = p * p;
  int t2 = t / pp;
  int c = t2 % NCH;
  int n = t2 / NCH;
  float2 st = stats[n * 8 + (c >> 2)];
  float v = __fadd_rn(__fmul_rn(__fmul_rn(__fsub_rn(buf[t], st.x), st.y), gamma[c]), beta[c]);
  float tt = __fdiv_rn(v, 1.41421356237309504880f);
  float e = (float)erf((double)tt);
  buf[t] = __fmul_rn(__fmul_rn(0.5f, v), __fadd_rn(1.0f, e));
}

// ---------------------------------------------------------------------------
// Argmin, monolithic vocab loop (first-occurrence preserved), embeddings
// streamed through double-buffered LDS tiles of 128 (coalesced float4 global
// loads prefetch tile t+1 during tile t's 8192-cycle FMA block; inner reads
// are ds_read_b128 broadcasts). Score chains bit-identical to round 5/6.
// ---------------------------------------------------------------------------
__global__ __launch_bounds__(256) void argmin_kernel(
    const float* __restrict__ z, const float* __restrict__ emb,
    const float* __restrict__ ee, float* __restrict__ zq,
    float* __restrict__ idxout, double* __restrict__ part) {
  __shared__ float4 ebuf[2][1024];          // 2 x (128 emb x 8 float4) = 32 KB
  __shared__ double red[256];
  int tid = threadIdx.x;
  int r = blockIdx.x * 256 + tid;           // grid exact: 576*256 rows
  const float* zr = z + (size_t)r * 32;
  const float4* esrc = (const float4*)emb;  // 16384 float4 total

  float zv[32];
#pragma unroll
  for (int q = 0; q < 32; q++) zv[q] = zr[q];

  // zz: numpy pairwise over 32 squares
  float rr[8];
#pragma unroll
  for (int j = 0; j < 8; j++) rr[j] = __fmul_rn(zv[j], zv[j]);
#pragma unroll
  for (int i = 8; i < 32; i += 8)
#pragma unroll
    for (int j = 0; j < 8; j++) rr[j] = __fadd_rn(rr[j], __fmul_rn(zv[i + j], zv[i + j]));
  float zz = __fadd_rn(__fadd_rn(__fadd_rn(rr[0], rr[1]), __fadd_rn(rr[2], rr[3])),
                       __fadd_rn(__fadd_rn(rr[4], rr[5]), __fadd_rn(rr[6], rr[7])));

  // stage tile 0
#pragma unroll
  for (int k = 0; k < 4; k++)
    ebuf[0][k * 256 + tid] = esrc[k * 256 + tid];
  __syncthreads();

  float best = 3.402823466e+38f;
  int bi = 0;
  for (int tl = 0; tl < 16; tl++) {
    int cur = tl & 1;
    if (tl + 1 < 16) {                      // prefetch next tile into other buf
#pragma unroll
      for (int k = 0; k < 4; k++)
        ebuf[cur ^ 1][k * 256 + tid] = esrc[(tl + 1) * 1024 + k * 256 + tid];
    }
    int v0 = tl * 128;
    for (int vl = 0; vl < 128; vl += 4) {
      const float* e0 = (const float*)&ebuf[cur][vl * 8];  // uniform -> broadcast
      float m0 = 0.0f, m1 = 0.0f, m2 = 0.0f, m3 = 0.0f;
#pragma unroll
      for (int q = 0; q < 32; q++) {
        m0 = fmaf(zv[q], e0[q], m0);
        m1 = fmaf(zv[q], e0[32 + q], m1);
        m2 = fmaf(zv[q], e0[64 + q], m2);
        m3 = fmaf(zv[q], e0[96 + q], m3);
      }
      int v = v0 + vl;
      float d0 = __fsub_rn(__fadd_rn(zz, ee[v]),     __fmul_rn(2.0f, m0));
      float d1 = __fsub_rn(__fadd_rn(zz, ee[v + 1]), __fmul_rn(2.0f, m1));
      float d2 = __fsub_rn(__fadd_rn(zz, ee[v + 2]), __fmul_rn(2.0f, m2));
      float d3 = __fsub_rn(__fadd_rn(zz, ee[v + 3]), __fmul_rn(2.0f, m3));
      if (d0 < best) { best = d0; bi = v; }
      if (d1 < best) { best = d1; bi = v + 1; }
      if (d2 < best) { best = d2; bi = v + 2; }
      if (d3 < best) { best = d3; bi = v + 3; }
    }
    __syncthreads();                        // cur fully read; cur^1 staged
  }

  double sse = 0.0;
#pragma unroll
  for (int q = 0; q < 32; q++) {
    float e = emb[bi * 32 + q];
    zq[(size_t)r * 32 + q] = e;
    double dd = (double)e - (double)zv[q];
    sse += dd * dd;
  }
  idxout[r] = (float)bi;

  red[tid] = sse;
  __syncthreads();
  for (int st = 128; st > 0; st >>= 1) {
    if (tid < st) red[tid] += red[tid + st];
    __syncthreads();
  }
  if (tid == 0) part[blockIdx.x] = red[0];
}

__global__ __launch_bounds__(256) void sigmoid_kernel(
    const float* __restrict__ acc, float* __restrict__ out) {
  int t = blockIdx.x * 256 + threadIdx.x;
  out[t] = (float)(1.0 / (1.0 + exp(-(double)acc[t])));
}

__global__ void loss_kernel(const double* __restrict__ part, float* __restrict__ out) {
  double tot = 0.0;
  for (int s = 0; s < 4; s++) {
    double sse = 0.0;
    for (int b = 0; b < 576; b++) sse += part[s * 1024 + b];
    tot += 1.25 * sse / 4718592.0;
  }
  out[0] = (float)tot;
}

// ---------------------------------------------------------------------------
extern "C" void kernel_launch(void* const* d_in, const int* in_sizes, int n_in,
                              void* d_out, int out_size, void* d_ws, size_t ws_size,
                              hipStream_t stream) {
  const float* X   = (const float*)d_in[0];
  const float* EMB = (const float*)d_in[1];
  const float* PW1 = (const float*)d_in[2];
  const float* PB1 = (const float*)d_in[3];
  const float* PG  = (const float*)d_in[4];
  const float* PBT = (const float*)d_in[5];
  const float* PW2 = (const float*)d_in[6];
  const float* PB2 = (const float*)d_in[7];
  const float* RW1 = (const float*)d_in[8];
  const float* RB1 = (const float*)d_in[9];
  const float* RG  = (const float*)d_in[10];
  const float* RBT = (const float*)d_in[11];
  const float* RW2 = (const float*)d_in[12];
  const float* RB2 = (const float*)d_in[13];
  float* out = (float*)d_out;

  // workspace layout (~55 MiB):
  //   EE    @ 0         (8,192)       f32 |e|^2
  //   WT    @ 8192      (589,824)     f32 transposed weights [16][288][32]
  //   STATS @ 598016    (36,864)      float2 per-(n,g) mu/rs
  //   PART  @ 634880    (32,768)      f64 SSE partials
  //   P     @ 667648    (18,874,368)  f32 patch-major buffer
  //   H     @ 19542016  (18,874,368)  f32 patch-major buffer
  //   ACC   @ 38416384  (18,874,368)  f32 image-layout accumulator
  char* w = (char*)d_ws;
  float*  EE    = (float*)(w);
  float*  WT    = (float*)(w + 8192UL);
  float2* STATS = (float2*)(w + 598016UL);
  double* PART  = (double*)(w + 634880UL);
  float*  P     = (float*)(w + 667648UL);
  float*  H     = (float*)(w + 19542016UL);
  float*  ACC   = (float*)(w + 38416384UL);

  hipMemsetAsync(ACC, 0, 18874368UL, stream);
  prep_kernel<<<584, 256, 0, stream>>>(PW1, PW2, RW1, RW2, EMB, WT, EE);

  const int PS[4] = {16, 32, 48, 64};
  for (int s = 0; s < 4; s++) {
    int p = PS[s], nw = 384 / p, N = nw * nw;
    const float* wt_p1 = WT + (0 * 4 + s) * 9216;
    const float* wt_p2 = WT + (1 * 4 + s) * 9216;
    const float* wt_r1 = WT + (2 * 4 + s) * 9216;
    const float* wt_r2 = WT + (3 * 4 + s) * 9216;

    // conv_block #1 (fused unfold): (x - acc) -> H, GN+GELU in H, H -> P (z)
    conv32_kernel<1><<<576, 256, 0, stream>>>(nullptr, X, ACC, H, nullptr, nullptr,
                                              wt_p1, PB1 + s * 32, p, nw);
    gn_stats_kernel<<<N, 64, 0, stream>>>(H, STATS, p);
    gn_gelu_kernel<<<18432, 256, 0, stream>>>(H, STATS, PG + s * 32, PBT + s * 32, p);
    conv32_kernel<0><<<576, 256, 0, stream>>>(H, nullptr, nullptr, P, nullptr, nullptr,
                                              wt_p2, PB2 + s * 32, p, nw);
    // quantize: z (P) -> idx, zq into H, SSE partials
    argmin_kernel<<<576, 256, 0, stream>>>(P, EMB, EE, H,
                                           out + 4718592 + s * 147456, PART + s * 1024);
    // residual conv_block on zq: H -> P, GN+GELU in P, conv+fold into ACC
    conv32_kernel<0><<<576, 256, 0, stream>>>(H, nullptr, nullptr, P, nullptr, nullptr,
                                              wt_r1, RB1 + s * 32, p, nw);
    gn_stats_kernel<<<N, 64, 0, stream>>>(P, STATS, p);
    gn_gelu_kernel<<<18432, 256, 0, stream>>>(P, STATS, RG + s * 32, RBT + s * 32, p);
    conv32_kernel<2><<<576, 256, 0, stream>>>(P, nullptr, nullptr, nullptr, H, ACC,
                                              wt_r2, RB2 + s * 32, p, nw);
  }

  sigmoid_kernel<<<18432, 256, 0, stream>>>(ACC, out);
  loss_kernel<<<1, 1, 0, stream>>>(PART, out + 5308416);
}

// Round 9
// 3315.820 us; speedup vs baseline: 2.6909x; 1.0488x over previous
//
#include <hip/hip_runtime.h>
#include <cmath>

#define WIDTH 384
#define HW 147456        // 384*384
#define CHW 4718592      // 32*384*384
#define NCH 32
#define NV 2048
#define NROWS 147456     // zf rows per scale

// ---------------------------------------------------------------------------
// numpy pairwise_sum replica, f32, contraction-proof.
// ---------------------------------------------------------------------------
template <int SQ>
__device__ float np_pw(const float* a, int n, float mu) {
  if (n < 8) {
    float res = 0.0f;
    for (int i = 0; i < n; i++) {
      float v = a[i];
      if (SQ) { float d = __fsub_rn(v, mu); v = __fmul_rn(d, d); }
      res = __fadd_rn(res, v);
    }
    return res;
  }
  if (n <= 128) {
    float r[8];
#pragma unroll
    for (int j = 0; j < 8; j++) {
      float v = a[j];
      if (SQ) { float d = __fsub_rn(v, mu); v = __fmul_rn(d, d); }
      r[j] = v;
    }
    int i;
    for (i = 8; i + 8 <= n; i += 8) {
#pragma unroll
      for (int j = 0; j < 8; j++) {
        float v = a[i + j];
        if (SQ) { float d = __fsub_rn(v, mu); v = __fmul_rn(d, d); }
        r[j] = __fadd_rn(r[j], v);
      }
    }
    float res = __fadd_rn(__fadd_rn(__fadd_rn(r[0], r[1]), __fadd_rn(r[2], r[3])),
                          __fadd_rn(__fadd_rn(r[4], r[5]), __fadd_rn(r[6], r[7])));
    for (; i < n; i++) {
      float v = a[i];
      if (SQ) { float d = __fsub_rn(v, mu); v = __fmul_rn(d, d); }
      res = __fadd_rn(res, v);
    }
    return res;
  }
  int n2 = n / 2; n2 -= n2 % 8;
  return __fadd_rn(np_pw<SQ>(a, n2, mu), np_pw<SQ>(a + n2, n - n2, mu));
}

// ---------------------------------------------------------------------------
// prep: ee[v] = numpy-pairwise |e|^2; WT = weights transposed to [layer][k][co]
// ---------------------------------------------------------------------------
__global__ __launch_bounds__(256) void prep_kernel(
    const float* __restrict__ pw1, const float* __restrict__ pw2,
    const float* __restrict__ rw1, const float* __restrict__ rw2,
    const float* __restrict__ emb, float* __restrict__ wt, float* __restrict__ ee) {
  int t = blockIdx.x * 256 + threadIdx.x;
  if (t < 147456) {
    int layer = t / 9216, r = t % 9216;
    int k = r / 32, co = r % 32;
    int set = layer >> 2, s = layer & 3;
    const float* src = set == 0 ? pw1 : set == 1 ? pw2 : set == 2 ? rw1 : rw2;
    wt[t] = src[s * 9216 + co * 288 + k];
  } else if (t < 147456 + NV) {
    int v = t - 147456;
    const float* e = emb + v * 32;
    float r[8];
#pragma unroll
    for (int j = 0; j < 8; j++) r[j] = __fmul_rn(e[j], e[j]);
#pragma unroll
    for (int i = 8; i < 32; i += 8)
#pragma unroll
      for (int j = 0; j < 8; j++) r[j] = __fadd_rn(r[j], __fmul_rn(e[i + j], e[i + j]));
    ee[v] = __fadd_rn(__fadd_rn(__fadd_rn(r[0], r[1]), __fadd_rn(r[2], r[3])),
                      __fadd_rn(__fadd_rn(r[4], r[5]), __fadd_rn(r[6], r[7])));
  }
}

// ---------------------------------------------------------------------------
// conv3x3: one thread = one pixel, ALL 32 co. Explicit double-buffered tap
// loads (tv = current ci, tn = prefetched ci+1) so the 9(18) loads of ci+1
// are issued before ci's 288-FMA block and their latency hides under it.
// Per-co chain order = (ci, dy, dx) ascending fmaf — bit-identical; invalid
// taps = exact identities. Weights via wave-uniform scalar loads.
// MODE 0: patch-major in -> patch-major out
// MODE 1: residual in (x - acc, image layout, fuses unfold) -> patch-major out
// MODE 2: patch-major in; fold: acc_img += zq*0.5 + (conv+b)*0.5
// ---------------------------------------------------------------------------
template <int MODE>
__global__ __launch_bounds__(256, 4) void conv32_kernel(
    const float* __restrict__ in, const float* __restrict__ x,
    const float* __restrict__ accin, float* __restrict__ outb,
    const float* __restrict__ zqb, float* __restrict__ acc,
    const float* __restrict__ wt, const float* __restrict__ bias, int p, int nw) {
  int t = blockIdx.x * 256 + threadIdx.x;   // grid exact: 576*256 = 147456
  int pp = p * p;
  int px = t % p; int t1 = t / p;
  int py = t1 % p;
  int n  = t1 / p;
  int i = n / nw, j = n % nw;

  int off[9]; bool msk[9];
#pragma unroll
  for (int dy = 0; dy < 3; dy++) {
    int ly = py + dy - 1;
    bool vy = (unsigned)ly < (unsigned)p;
    int cy = vy ? ly : 0;
#pragma unroll
    for (int dx = 0; dx < 3; dx++) {
      int lx = px + dx - 1;
      bool vx = (unsigned)lx < (unsigned)p;
      int cx = vx ? lx : 0;
      msk[dy * 3 + dx] = vy && vx;
      if (MODE == 1) off[dy * 3 + dx] = (i * p + cy) * WIDTH + (j * p + cx);
      else           off[dy * 3 + dx] = cy * p + cx;
    }
  }

  const float* pin = (MODE == 1) ? nullptr : in + (size_t)n * NCH * pp;

  float a[NCH];
#pragma unroll
  for (int co = 0; co < NCH; co++) a[co] = 0.0f;

  float tv[9], tn[9];
#pragma unroll
  for (int k = 0; k < 9; k++) {             // load ci = 0
    float v;
    if (MODE == 1) {
      size_t ad = (size_t)off[k];
      v = __fsub_rn(x[ad], accin[ad]);
    } else {
      v = pin[off[k]];
    }
    tv[k] = msk[k] ? v : 0.0f;
  }

  for (int ci = 0; ci < NCH; ci++) {
    if (ci + 1 < NCH) {                     // prefetch ci+1 taps
#pragma unroll
      for (int k = 0; k < 9; k++) {
        float v;
        if (MODE == 1) {
          size_t ad = (size_t)(ci + 1) * HW + off[k];
          v = __fsub_rn(x[ad], accin[ad]);
        } else {
          v = pin[(size_t)(ci + 1) * pp + off[k]];
        }
        tn[k] = msk[k] ? v : 0.0f;
      }
    }
    const float* wp = wt + ci * 288;        // [k][co], uniform -> s_load
#pragma unroll
    for (int k = 0; k < 9; k++) {
#pragma unroll
      for (int co = 0; co < NCH; co++)
        a[co] = fmaf(tv[k], wp[k * 32 + co], a[co]);
    }
#pragma unroll
    for (int k = 0; k < 9; k++) tv[k] = tn[k];
  }

#pragma unroll
  for (int co = 0; co < NCH; co++) {
    float r = __fadd_rn(a[co], bias[co]);
    if (MODE == 2) {
      size_t img = (size_t)co * HW + (size_t)(i * p + py) * WIDTH + (j * p + px);
      size_t pt  = (size_t)n * NCH * pp + (size_t)co * pp + (size_t)py * p + px;
      float dec = __fadd_rn(__fmul_rn(zqb[pt], 0.5f), __fmul_rn(r, 0.5f));
      acc[img] = __fadd_rn(acc[img], dec);
    } else {
      outb[(size_t)n * NCH * pp + (size_t)co * pp + (size_t)py * p + px] = r;
    }
  }
}

// ---------------------------------------------------------------------------
// GroupNorm stats, numpy-exact (unchanged).
// ---------------------------------------------------------------------------
__global__ __launch_bounds__(64) void gn_stats_kernel(
    const float* __restrict__ buf, float2* __restrict__ stats, int p) {
  __shared__ float lds[8][8];
  __shared__ float mus[8];
  int gi = threadIdx.x >> 3, l = threadIdx.x & 7;
  int grp = blockIdx.x * 8 + gi;
  int pp = p * p, ne = 4 * pp, chunk = ne >> 3;
  const float* base = buf + ((size_t)(grp >> 3) * NCH + (size_t)(grp & 7) * 4) * pp;

  lds[gi][l] = np_pw<0>(base + l * chunk, chunk, 0.0f);
  __syncthreads();
  if (l == 0) {
    float* r = lds[gi];
    float s = __fadd_rn(__fadd_rn(__fadd_rn(r[0], r[1]), __fadd_rn(r[2], r[3])),
                        __fadd_rn(__fadd_rn(r[4], r[5]), __fadd_rn(r[6], r[7])));
    mus[gi] = __fdiv_rn(s, (float)ne);
  }
  __syncthreads();
  float mu = mus[gi];
  lds[gi][l] = np_pw<1>(base + l * chunk, chunk, mu);
  __syncthreads();
  if (l == 0) {
    float* r = lds[gi];
    float s2 = __fadd_rn(__fadd_rn(__fadd_rn(r[0], r[1]), __fadd_rn(r[2], r[3])),
                         __fadd_rn(__fadd_rn(r[4], r[5]), __fadd_rn(r[6], r[7])));
    float var = __fdiv_rn(s2, (float)ne);
    float rs = __fdiv_rn(1.0f, __fsqrt_rn(__fadd_rn(var, 1e-5f)));
    stats[grp] = make_float2(mu, rs);
  }
}

// ---------------------------------------------------------------------------
// GN affine + exact GELU (unchanged; erf = f64 erf rounded to f32).
// ---------------------------------------------------------------------------
__global__ __launch_bounds__(256) void gn_gelu_kernel(
    float* __restrict__ buf, const float2* __restrict__ stats,
    const float* __restrict__ gamma, const float* __restrict__ beta, int p) {
  int t = blockIdx.x * 256 + threadIdx.x;
  int pp = p * p;
  int t2 = t / pp;
  int c = t2 % NCH;
  int n = t2 / NCH;
  float2 st = stats[n * 8 + (c >> 2)];
  float v = __fadd_rn(__fmul_rn(__fmul_rn(__fsub_rn(buf[t], st.x), st.y), gamma[c]), beta[c]);
  float tt = __fdiv_rn(v, 1.41421356237309504880f);
  float e = (float)erf((double)tt);
  buf[t] = __fmul_rn(__fmul_rn(0.5f, v), __fadd_rn(1.0f, e));
}

// ---------------------------------------------------------------------------
// Argmin, monolithic vocab loop (first-occurrence preserved), embeddings
// streamed through double-buffered LDS tiles of 128. 8-wide embedding unroll:
// 8 independent 32-FMA chains per group (per-chain ascending-q fmaf order
// unchanged -> bit-exact); compares resolved in ascending v order.
// ---------------------------------------------------------------------------
__global__ __launch_bounds__(256, 4) void argmin_kernel(
    const float* __restrict__ z, const float* __restrict__ emb,
    const float* __restrict__ ee, float* __restrict__ zq,
    float* __restrict__ idxout, double* __restrict__ part) {
  __shared__ float4 ebuf[2][1024];          // 2 x (128 emb x 8 float4) = 32 KB
  __shared__ double red[256];
  int tid = threadIdx.x;
  int r = blockIdx.x * 256 + tid;           // grid exact: 576*256 rows
  const float* zr = z + (size_t)r * 32;
  const float4* esrc = (const float4*)emb;  // 16384 float4 total

  float zv[32];
#pragma unroll
  for (int q = 0; q < 32; q++) zv[q] = zr[q];

  // zz: numpy pairwise over 32 squares
  float rr[8];
#pragma unroll
  for (int j = 0; j < 8; j++) rr[j] = __fmul_rn(zv[j], zv[j]);
#pragma unroll
  for (int i = 8; i < 32; i += 8)
#pragma unroll
    for (int j = 0; j < 8; j++) rr[j] = __fadd_rn(rr[j], __fmul_rn(zv[i + j], zv[i + j]));
  float zz = __fadd_rn(__fadd_rn(__fadd_rn(rr[0], rr[1]), __fadd_rn(rr[2], rr[3])),
                       __fadd_rn(__fadd_rn(rr[4], rr[5]), __fadd_rn(rr[6], rr[7])));

  // stage tile 0
#pragma unroll
  for (int k = 0; k < 4; k++)
    ebuf[0][k * 256 + tid] = esrc[k * 256 + tid];
  __syncthreads();

  float best = 3.402823466e+38f;
  int bi = 0;
  for (int tl = 0; tl < 16; tl++) {
    int cur = tl & 1;
    if (tl + 1 < 16) {                      // prefetch next tile into other buf
#pragma unroll
      for (int k = 0; k < 4; k++)
        ebuf[cur ^ 1][k * 256 + tid] = esrc[(tl + 1) * 1024 + k * 256 + tid];
    }
    int v0 = tl * 128;
    for (int vl = 0; vl < 128; vl += 8) {
      const float* e0 = (const float*)&ebuf[cur][vl * 8];  // uniform -> broadcast
      float m[8];
#pragma unroll
      for (int j = 0; j < 8; j++) m[j] = 0.0f;
#pragma unroll
      for (int q = 0; q < 32; q++) {
#pragma unroll
        for (int j = 0; j < 8; j++)
          m[j] = fmaf(zv[q], e0[j * 32 + q], m[j]);
      }
      int v = v0 + vl;
#pragma unroll
      for (int j = 0; j < 8; j++) {
        float d = __fsub_rn(__fadd_rn(zz, ee[v + j]), __fmul_rn(2.0f, m[j]));
        if (d < best) { best = d; bi = v + j; }
      }
    }
    __syncthreads();                        // cur fully read; cur^1 staged
  }

  double sse = 0.0;
#pragma unroll
  for (int q = 0; q < 32; q++) {
    float e = emb[bi * 32 + q];
    zq[(size_t)r * 32 + q] = e;
    double dd = (double)e - (double)zv[q];
    sse += dd * dd;
  }
  idxout[r] = (float)bi;

  red[tid] = sse;
  __syncthreads();
  for (int st = 128; st > 0; st >>= 1) {
    if (tid < st) red[tid] += red[tid + st];
    __syncthreads();
  }
  if (tid == 0) part[blockIdx.x] = red[0];
}

__global__ __launch_bounds__(256) void sigmoid_kernel(
    const float* __restrict__ acc, float* __restrict__ out) {
  int t = blockIdx.x * 256 + threadIdx.x;
  out[t] = (float)(1.0 / (1.0 + exp(-(double)acc[t])));
}

__global__ void loss_kernel(const double* __restrict__ part, float* __restrict__ out) {
  double tot = 0.0;
  for (int s = 0; s < 4; s++) {
    double sse = 0.0;
    for (int b = 0; b < 576; b++) sse += part[s * 1024 + b];
    tot += 1.25 * sse / 4718592.0;
  }
  out[0] = (float)tot;
}

// ---------------------------------------------------------------------------
extern "C" void kernel_launch(void* const* d_in, const int* in_sizes, int n_in,
                              void* d_out, int out_size, void* d_ws, size_t ws_size,
                              hipStream_t stream) {
  const float* X   = (const float*)d_in[0];
  const float* EMB = (const float*)d_in[1];
  const float* PW1 = (const float*)d_in[2];
  const float* PB1 = (const float*)d_in[3];
  const float* PG  = (const float*)d_in[4];
  const float* PBT = (const float*)d_in[5];
  const float* PW2 = (const float*)d_in[6];
  const float* PB2 = (const float*)d_in[7];
  const float* RW1 = (const float*)d_in[8];
  const float* RB1 = (const float*)d_in[9];
  const float* RG  = (const float*)d_in[10];
  const float* RBT = (const float*)d_in[11];
  const float* RW2 = (const float*)d_in[12];
  const float* RB2 = (const float*)d_in[13];
  float* out = (float*)d_out;

  // workspace layout (~55 MiB):
  //   EE    @ 0         (8,192)       f32 |e|^2
  //   WT    @ 8192      (589,824)     f32 transposed weights [16][288][32]
  //   STATS @ 598016    (36,864)      float2 per-(n,g) mu/rs
  //   PART  @ 634880    (32,768)      f64 SSE partials
  //   P     @ 667648    (18,874,368)  f32 patch-major buffer
  //   H     @ 19542016  (18,874,368)  f32 patch-major buffer
  //   ACC   @ 38416384  (18,874,368)  f32 image-layout accumulator
  char* w = (char*)d_ws;
  float*  EE    = (float*)(w);
  float*  WT    = (float*)(w + 8192UL);
  float2* STATS = (float2*)(w + 598016UL);
  double* PART  = (double*)(w + 634880UL);
  float*  P     = (float*)(w + 667648UL);
  float*  H     = (float*)(w + 19542016UL);
  float*  ACC   = (float*)(w + 38416384UL);

  hipMemsetAsync(ACC, 0, 18874368UL, stream);
  prep_kernel<<<584, 256, 0, stream>>>(PW1, PW2, RW1, RW2, EMB, WT, EE);

  const int PS[4] = {16, 32, 48, 64};
  for (int s = 0; s < 4; s++) {
    int p = PS[s], nw = 384 / p, N = nw * nw;
    const float* wt_p1 = WT + (0 * 4 + s) * 9216;
    const float* wt_p2 = WT + (1 * 4 + s) * 9216;
    const float* wt_r1 = WT + (2 * 4 + s) * 9216;
    const float* wt_r2 = WT + (3 * 4 + s) * 9216;

    // conv_block #1 (fused unfold): (x - acc) -> H, GN+GELU in H, H -> P (z)
    conv32_kernel<1><<<576, 256, 0, stream>>>(nullptr, X, ACC, H, nullptr, nullptr,
                                              wt_p1, PB1 + s * 32, p, nw);
    gn_stats_kernel<<<N, 64, 0, stream>>>(H, STATS, p);
    gn_gelu_kernel<<<18432, 256, 0, stream>>>(H, STATS, PG + s * 32, PBT + s * 32, p);
    conv32_kernel<0><<<576, 256, 0, stream>>>(H, nullptr, nullptr, P, nullptr, nullptr,
                                              wt_p2, PB2 + s * 32, p, nw);
    // quantize: z (P) -> idx, zq into H, SSE partials
    argmin_kernel<<<576, 256, 0, stream>>>(P, EMB, EE, H,
                                           out + 4718592 + s * 147456, PART + s * 1024);
    // residual conv_block on zq: H -> P, GN+GELU in P, conv+fold into ACC
    conv32_kernel<0><<<576, 256, 0, stream>>>(H, nullptr, nullptr, P, nullptr, nullptr,
                                              wt_r1, RB1 + s * 32, p, nw);
    gn_stats_kernel<<<N, 64, 0, stream>>>(P, STATS, p);
    gn_gelu_kernel<<<18432, 256, 0, stream>>>(P, STATS, RG + s * 32, RBT + s * 32, p);
    conv32_kernel<2><<<576, 256, 0, stream>>>(P, nullptr, nullptr, nullptr, H, ACC,
                                              wt_r2, RB2 + s * 32, p, nw);
  }

  sigmoid_kernel<<<18432, 256, 0, stream>>>(ACC, out);
  loss_kernel<<<1, 1, 0, stream>>>(PART, out + 5308416);
}

// Round 10
// 3223.650 us; speedup vs baseline: 2.7678x; 1.0286x over previous
//
#include <hip/hip_runtime.h>
#include <cmath>

#define WIDTH 384
#define HW 147456        // 384*384
#define CHW 4718592      // 32*384*384
#define NCH 32
#define NV 2048
#define NROWS 147456     // zf rows per scale

// ---------------------------------------------------------------------------
// numpy pairwise_sum replica, f32, contraction-proof.
// ---------------------------------------------------------------------------
template <int SQ>
__device__ float np_pw(const float* a, int n, float mu) {
  if (n < 8) {
    float res = 0.0f;
    for (int i = 0; i < n; i++) {
      float v = a[i];
      if (SQ) { float d = __fsub_rn(v, mu); v = __fmul_rn(d, d); }
      res = __fadd_rn(res, v);
    }
    return res;
  }
  if (n <= 128) {
    float r[8];
#pragma unroll
    for (int j = 0; j < 8; j++) {
      float v = a[j];
      if (SQ) { float d = __fsub_rn(v, mu); v = __fmul_rn(d, d); }
      r[j] = v;
    }
    int i;
    for (i = 8; i + 8 <= n; i += 8) {
#pragma unroll
      for (int j = 0; j < 8; j++) {
        float v = a[i + j];
        if (SQ) { float d = __fsub_rn(v, mu); v = __fmul_rn(d, d); }
        r[j] = __fadd_rn(r[j], v);
      }
    }
    float res = __fadd_rn(__fadd_rn(__fadd_rn(r[0], r[1]), __fadd_rn(r[2], r[3])),
                          __fadd_rn(__fadd_rn(r[4], r[5]), __fadd_rn(r[6], r[7])));
    for (; i < n; i++) {
      float v = a[i];
      if (SQ) { float d = __fsub_rn(v, mu); v = __fmul_rn(d, d); }
      res = __fadd_rn(res, v);
    }
    return res;
  }
  int n2 = n / 2; n2 -= n2 % 8;
  return __fadd_rn(np_pw<SQ>(a, n2, mu), np_pw<SQ>(a + n2, n - n2, mu));
}

// ---------------------------------------------------------------------------
// prep: ee[v] = numpy-pairwise |e|^2; WT = weights transposed to [layer][k][co]
// ---------------------------------------------------------------------------
__global__ __launch_bounds__(256) void prep_kernel(
    const float* __restrict__ pw1, const float* __restrict__ pw2,
    const float* __restrict__ rw1, const float* __restrict__ rw2,
    const float* __restrict__ emb, float* __restrict__ wt, float* __restrict__ ee) {
  int t = blockIdx.x * 256 + threadIdx.x;
  if (t < 147456) {
    int layer = t / 9216, r = t % 9216;
    int k = r / 32, co = r % 32;
    int set = layer >> 2, s = layer & 3;
    const float* src = set == 0 ? pw1 : set == 1 ? pw2 : set == 2 ? rw1 : rw2;
    wt[t] = src[s * 9216 + co * 288 + k];
  } else if (t < 147456 + NV) {
    int v = t - 147456;
    const float* e = emb + v * 32;
    float r[8];
#pragma unroll
    for (int j = 0; j < 8; j++) r[j] = __fmul_rn(e[j], e[j]);
#pragma unroll
    for (int i = 8; i < 32; i += 8)
#pragma unroll
      for (int j = 0; j < 8; j++) r[j] = __fadd_rn(r[j], __fmul_rn(e[i + j], e[i + j]));
    ee[v] = __fadd_rn(__fadd_rn(__fadd_rn(r[0], r[1]), __fadd_rn(r[2], r[3])),
                      __fadd_rn(__fadd_rn(r[4], r[5]), __fadd_rn(r[6], r[7])));
  }
}

// ---------------------------------------------------------------------------
// conv3x3: one thread = one pixel, ALL 32 co. 192-thread blocks, 768 blocks
// = exactly 3 blocks (9 waves) per CU -> even CU load (576x256 left 64 CUs
// with 3 blocks vs 192 with 2: 1.5x tail). Explicit tap double-buffer (tv
// current ci, tn prefetch ci+1). Per-co chain order = (ci, dy, dx) ascending
// fmaf — bit-identical; invalid taps exact identities. Weights via
// wave-uniform scalar loads.
// MODE 0: patch-major in -> patch-major out
// MODE 1: residual in (x - acc, image layout, fuses unfold) -> patch-major out
// MODE 2: patch-major in; fold: acc_img += zq*0.5 + (conv+b)*0.5
// ---------------------------------------------------------------------------
template <int MODE>
__global__ __launch_bounds__(192, 3) void conv32_kernel(
    const float* __restrict__ in, const float* __restrict__ x,
    const float* __restrict__ accin, float* __restrict__ outb,
    const float* __restrict__ zqb, float* __restrict__ acc,
    const float* __restrict__ wt, const float* __restrict__ bias, int p, int nw) {
  int t = blockIdx.x * 192 + threadIdx.x;   // grid exact: 768*192 = 147456
  int pp = p * p;
  int px = t % p; int t1 = t / p;
  int py = t1 % p;
  int n  = t1 / p;
  int i = n / nw, j = n % nw;

  int off[9]; bool msk[9];
#pragma unroll
  for (int dy = 0; dy < 3; dy++) {
    int ly = py + dy - 1;
    bool vy = (unsigned)ly < (unsigned)p;
    int cy = vy ? ly : 0;
#pragma unroll
    for (int dx = 0; dx < 3; dx++) {
      int lx = px + dx - 1;
      bool vx = (unsigned)lx < (unsigned)p;
      int cx = vx ? lx : 0;
      msk[dy * 3 + dx] = vy && vx;
      if (MODE == 1) off[dy * 3 + dx] = (i * p + cy) * WIDTH + (j * p + cx);
      else           off[dy * 3 + dx] = cy * p + cx;
    }
  }

  const float* pin = (MODE == 1) ? nullptr : in + (size_t)n * NCH * pp;

  float a[NCH];
#pragma unroll
  for (int co = 0; co < NCH; co++) a[co] = 0.0f;

  float tv[9], tn[9];
#pragma unroll
  for (int k = 0; k < 9; k++) {             // load ci = 0
    float v;
    if (MODE == 1) {
      size_t ad = (size_t)off[k];
      v = __fsub_rn(x[ad], accin[ad]);
    } else {
      v = pin[off[k]];
    }
    tv[k] = msk[k] ? v : 0.0f;
  }

  for (int ci = 0; ci < NCH; ci++) {
    if (ci + 1 < NCH) {                     // prefetch ci+1 taps
#pragma unroll
      for (int k = 0; k < 9; k++) {
        float v;
        if (MODE == 1) {
          size_t ad = (size_t)(ci + 1) * HW + off[k];
          v = __fsub_rn(x[ad], accin[ad]);
        } else {
          v = pin[(size_t)(ci + 1) * pp + off[k]];
        }
        tn[k] = msk[k] ? v : 0.0f;
      }
    }
    const float* wp = wt + ci * 288;        // [k][co], uniform -> s_load
#pragma unroll
    for (int k = 0; k < 9; k++) {
#pragma unroll
      for (int co = 0; co < NCH; co++)
        a[co] = fmaf(tv[k], wp[k * 32 + co], a[co]);
    }
#pragma unroll
    for (int k = 0; k < 9; k++) tv[k] = tn[k];
  }

#pragma unroll
  for (int co = 0; co < NCH; co++) {
    float r = __fadd_rn(a[co], bias[co]);
    if (MODE == 2) {
      size_t img = (size_t)co * HW + (size_t)(i * p + py) * WIDTH + (j * p + px);
      size_t pt  = (size_t)n * NCH * pp + (size_t)co * pp + (size_t)py * p + px;
      float dec = __fadd_rn(__fmul_rn(zqb[pt], 0.5f), __fmul_rn(r, 0.5f));
      acc[img] = __fadd_rn(acc[img], dec);
    } else {
      outb[(size_t)n * NCH * pp + (size_t)co * pp + (size_t)py * p + px] = r;
    }
  }
}

// ---------------------------------------------------------------------------
// GroupNorm stats, numpy-exact (unchanged).
// ---------------------------------------------------------------------------
__global__ __launch_bounds__(64) void gn_stats_kernel(
    const float* __restrict__ buf, float2* __restrict__ stats, int p) {
  __shared__ float lds[8][8];
  __shared__ float mus[8];
  int gi = threadIdx.x >> 3, l = threadIdx.x & 7;
  int grp = blockIdx.x * 8 + gi;
  int pp = p * p, ne = 4 * pp, chunk = ne >> 3;
  const float* base = buf + ((size_t)(grp >> 3) * NCH + (size_t)(grp & 7) * 4) * pp;

  lds[gi][l] = np_pw<0>(base + l * chunk, chunk, 0.0f);
  __syncthreads();
  if (l == 0) {
    float* r = lds[gi];
    float s = __fadd_rn(__fadd_rn(__fadd_rn(r[0], r[1]), __fadd_rn(r[2], r[3])),
                        __fadd_rn(__fadd_rn(r[4], r[5]), __fadd_rn(r[6], r[7])));
    mus[gi] = __fdiv_rn(s, (float)ne);
  }
  __syncthreads();
  float mu = mus[gi];
  lds[gi][l] = np_pw<1>(base + l * chunk, chunk, mu);
  __syncthreads();
  if (l == 0) {
    float* r = lds[gi];
    float s2 = __fadd_rn(__fadd_rn(__fadd_rn(r[0], r[1]), __fadd_rn(r[2], r[3])),
                         __fadd_rn(__fadd_rn(r[4], r[5]), __fadd_rn(r[6], r[7])));
    float var = __fdiv_rn(s2, (float)ne);
    float rs = __fdiv_rn(1.0f, __fsqrt_rn(__fadd_rn(var, 1e-5f)));
    stats[grp] = make_float2(mu, rs);
  }
}

// ---------------------------------------------------------------------------
// GN affine + exact GELU (unchanged; erf = f64 erf rounded to f32).
// ---------------------------------------------------------------------------
__global__ __launch_bounds__(256) void gn_gelu_kernel(
    float* __restrict__ buf, const float2* __restrict__ stats,
    const float* __restrict__ gamma, const float* __restrict__ beta, int p) {
  int t = blockIdx.x * 256 + threadIdx.x;
  int pp = p * p;
  int t2 = t / pp;
  int c = t2 % NCH;
  int n = t2 / NCH;
  float2 st = stats[n * 8 + (c >> 2)];
  float v = __fadd_rn(__fmul_rn(__fmul_rn(__fsub_rn(buf[t], st.x), st.y), gamma[c]), beta[c]);
  float tt = __fdiv_rn(v, 1.41421356237309504880f);
  float e = (float)erf((double)tt);
  buf[t] = __fmul_rn(__fmul_rn(0.5f, v), __fadd_rn(1.0f, e));
}

// ---------------------------------------------------------------------------
// Argmin, monolithic vocab loop (first-occurrence preserved), embeddings via
// double-buffered LDS tiles of 128. 192-thread blocks, 768 blocks = exactly
// 3 blocks/CU (even load). 8-wide embedding unroll, per-chain ascending-q
// fmaf order unchanged -> bit-exact; compares in ascending v order.
// ---------------------------------------------------------------------------
__global__ __launch_bounds__(192, 3) void argmin_kernel(
    const float* __restrict__ z, const float* __restrict__ emb,
    const float* __restrict__ ee, float* __restrict__ zq,
    float* __restrict__ idxout, double* __restrict__ part) {
  __shared__ float4 ebuf[2][1024];          // 2 x (128 emb x 8 float4) = 32 KB
  __shared__ double red[192];
  int tid = threadIdx.x;
  int r = blockIdx.x * 192 + tid;           // grid exact: 768*192 rows
  const float* zr = z + (size_t)r * 32;
  const float4* esrc = (const float4*)emb;  // 16384 float4 total

  float zv[32];
#pragma unroll
  for (int q = 0; q < 32; q++) zv[q] = zr[q];

  // zz: numpy pairwise over 32 squares
  float rr[8];
#pragma unroll
  for (int j = 0; j < 8; j++) rr[j] = __fmul_rn(zv[j], zv[j]);
#pragma unroll
  for (int i = 8; i < 32; i += 8)
#pragma unroll
    for (int j = 0; j < 8; j++) rr[j] = __fadd_rn(rr[j], __fmul_rn(zv[i + j], zv[i + j]));
  float zz = __fadd_rn(__fadd_rn(__fadd_rn(rr[0], rr[1]), __fadd_rn(rr[2], rr[3])),
                       __fadd_rn(__fadd_rn(rr[4], rr[5]), __fadd_rn(rr[6], rr[7])));

  // stage tile 0
  for (int idx = tid; idx < 1024; idx += 192)
    ebuf[0][idx] = esrc[idx];
  __syncthreads();

  float best = 3.402823466e+38f;
  int bi = 0;
  for (int tl = 0; tl < 16; tl++) {
    int cur = tl & 1;
    if (tl + 1 < 16) {                      // prefetch next tile into other buf
      for (int idx = tid; idx < 1024; idx += 192)
        ebuf[cur ^ 1][idx] = esrc[(tl + 1) * 1024 + idx];
    }
    int v0 = tl * 128;
    for (int vl = 0; vl < 128; vl += 8) {
      const float* e0 = (const float*)&ebuf[cur][vl * 8];  // uniform -> broadcast
      float m[8];
#pragma unroll
      for (int j = 0; j < 8; j++) m[j] = 0.0f;
#pragma unroll
      for (int q = 0; q < 32; q++) {
#pragma unroll
        for (int j = 0; j < 8; j++)
          m[j] = fmaf(zv[q], e0[j * 32 + q], m[j]);
      }
      int v = v0 + vl;
#pragma unroll
      for (int j = 0; j < 8; j++) {
        float d = __fsub_rn(__fadd_rn(zz, ee[v + j]), __fmul_rn(2.0f, m[j]));
        if (d < best) { best = d; bi = v + j; }
      }
    }
    __syncthreads();                        // cur fully read; cur^1 staged
  }

  double sse = 0.0;
#pragma unroll
  for (int q = 0; q < 32; q++) {
    float e = emb[bi * 32 + q];
    zq[(size_t)r * 32 + q] = e;
    double dd = (double)e - (double)zv[q];
    sse += dd * dd;
  }
  idxout[r] = (float)bi;

  red[tid] = sse;
  __syncthreads();
  if (tid < 64) red[tid] = red[tid] + red[tid + 64] + red[tid + 128];
  __syncthreads();
  for (int st = 32; st > 0; st >>= 1) {
    if (tid < st) red[tid] += red[tid + st];
    __syncthreads();
  }
  if (tid == 0) part[blockIdx.x] = red[0];
}

__global__ __launch_bounds__(256) void sigmoid_kernel(
    const float* __restrict__ acc, float* __restrict__ out) {
  int t = blockIdx.x * 256 + threadIdx.x;
  out[t] = (float)(1.0 / (1.0 + exp(-(double)acc[t])));
}

__global__ void loss_kernel(const double* __restrict__ part, float* __restrict__ out) {
  double tot = 0.0;
  for (int s = 0; s < 4; s++) {
    double sse = 0.0;
    for (int b = 0; b < 768; b++) sse += part[s * 1024 + b];
    tot += 1.25 * sse / 4718592.0;
  }
  out[0] = (float)tot;
}

// ---------------------------------------------------------------------------
extern "C" void kernel_launch(void* const* d_in, const int* in_sizes, int n_in,
                              void* d_out, int out_size, void* d_ws, size_t ws_size,
                              hipStream_t stream) {
  const float* X   = (const float*)d_in[0];
  const float* EMB = (const float*)d_in[1];
  const float* PW1 = (const float*)d_in[2];
  const float* PB1 = (const float*)d_in[3];
  const float* PG  = (const float*)d_in[4];
  const float* PBT = (const float*)d_in[5];
  const float* PW2 = (const float*)d_in[6];
  const float* PB2 = (const float*)d_in[7];
  const float* RW1 = (const float*)d_in[8];
  const float* RB1 = (const float*)d_in[9];
  const float* RG  = (const float*)d_in[10];
  const float* RBT = (const float*)d_in[11];
  const float* RW2 = (const float*)d_in[12];
  const float* RB2 = (const float*)d_in[13];
  float* out = (float*)d_out;

  // workspace layout (~55 MiB):
  //   EE    @ 0         (8,192)       f32 |e|^2
  //   WT    @ 8192      (589,824)     f32 transposed weights [16][288][32]
  //   STATS @ 598016    (36,864)      float2 per-(n,g) mu/rs
  //   PART  @ 634880    (32,768)      f64 SSE partials (1024 per scale, 768 used)
  //   P     @ 667648    (18,874,368)  f32 patch-major buffer
  //   H     @ 19542016  (18,874,368)  f32 patch-major buffer
  //   ACC   @ 38416384  (18,874,368)  f32 image-layout accumulator
  char* w = (char*)d_ws;
  float*  EE    = (float*)(w);
  float*  WT    = (float*)(w + 8192UL);
  float2* STATS = (float2*)(w + 598016UL);
  double* PART  = (double*)(w + 634880UL);
  float*  P     = (float*)(w + 667648UL);
  float*  H     = (float*)(w + 19542016UL);
  float*  ACC   = (float*)(w + 38416384UL);

  hipMemsetAsync(ACC, 0, 18874368UL, stream);
  prep_kernel<<<584, 256, 0, stream>>>(PW1, PW2, RW1, RW2, EMB, WT, EE);

  const int PS[4] = {16, 32, 48, 64};
  for (int s = 0; s < 4; s++) {
    int p = PS[s], nw = 384 / p, N = nw * nw;
    const float* wt_p1 = WT + (0 * 4 + s) * 9216;
    const float* wt_p2 = WT + (1 * 4 + s) * 9216;
    const float* wt_r1 = WT + (2 * 4 + s) * 9216;
    const float* wt_r2 = WT + (3 * 4 + s) * 9216;

    // conv_block #1 (fused unfold): (x - acc) -> H, GN+GELU in H, H -> P (z)
    conv32_kernel<1><<<768, 192, 0, stream>>>(nullptr, X, ACC, H, nullptr, nullptr,
                                              wt_p1, PB1 + s * 32, p, nw);
    gn_stats_kernel<<<N, 64, 0, stream>>>(H, STATS, p);
    gn_gelu_kernel<<<18432, 256, 0, stream>>>(H, STATS, PG + s * 32, PBT + s * 32, p);
    conv32_kernel<0><<<768, 192, 0, stream>>>(H, nullptr, nullptr, P, nullptr, nullptr,
                                              wt_p2, PB2 + s * 32, p, nw);
    // quantize: z (P) -> idx, zq into H, SSE partials
    argmin_kernel<<<768, 192, 0, stream>>>(P, EMB, EE, H,
                                           out + 4718592 + s * 147456, PART + s * 1024);
    // residual conv_block on zq: H -> P, GN+GELU in P, conv+fold into ACC
    conv32_kernel<0><<<768, 192, 0, stream>>>(H, nullptr, nullptr, P, nullptr, nullptr,
                                              wt_r1, RB1 + s * 32, p, nw);
    gn_stats_kernel<<<N, 64, 0, stream>>>(P, STATS, p);
    gn_gelu_kernel<<<18432, 256, 0, stream>>>(P, STATS, RG + s * 32, RBT + s * 32, p);
    conv32_kernel<2><<<768, 192, 0, stream>>>(P, nullptr, nullptr, nullptr, H, ACC,
                                              wt_r2, RB2 + s * 32, p, nw);
  }

  sigmoid_kernel<<<18432, 256, 0, stream>>>(ACC, out);
  loss_kernel<<<1, 1, 0, stream>>>(PART, out + 5308416);
}